// Round 6
// baseline (2009.756 us; speedup 1.0000x reference)
//
#include <hip/hip_runtime.h>

#define BATCH 512
#define TT    256
#define II    256
#define HH    512

typedef float f32x4  __attribute__((ext_vector_type(4)));
typedef unsigned u32x4 __attribute__((ext_vector_type(4)));
typedef unsigned short u16x8 __attribute__((ext_vector_type(8)));
typedef short bfrag  __attribute__((ext_vector_type(8)));   // 8 bf16 = 4 VGPRs (MFMA A/B operand)

__device__ inline unsigned short f2bf(float f) {
    unsigned u = __float_as_uint(f);
    return (unsigned short)((u + 0x7fffu + ((u >> 16) & 1u)) >> 16);   // RNE
}
__device__ inline float bf2f(unsigned short h) { return __uint_as_float(((unsigned)h) << 16); }

__device__ inline bfrag cvt8(const float* p) {   // 8 fp32 -> bf16 frag
    float4 a = *(const float4*)p;
    float4 b = *(const float4*)(p + 4);
    u16x8 u;
    u[0]=f2bf(a.x); u[1]=f2bf(a.y); u[2]=f2bf(a.z); u[3]=f2bf(a.w);
    u[4]=f2bf(b.x); u[5]=f2bf(b.y); u[6]=f2bf(b.z); u[7]=f2bf(b.w);
    return __builtin_bit_cast(bfrag, u);
}
__device__ inline bfrag ld8(const unsigned short* p) {
    return __builtin_bit_cast(bfrag, *(const u16x8*)p);
}
__device__ inline float sigm(float x) { return 1.f / (1.f + __expf(-x)); }
__device__ inline float tanh_(float x) {       // overflow-safe tanh via exp
    float ax = fabsf(x);
    float e  = __expf(-2.f * ax);
    float t  = (1.f - e) / (1.f + e);
    return copysignf(t, x);
}

// ---------------- x -> bf16 cast + transpose (B,T,I) -> (T,B,I) ----------------
__global__ __launch_bounds__(256) void cast_x_kernel(const float* __restrict__ x,
                                                     unsigned short* __restrict__ xt) {
    int b  = blockIdx.x >> 2;
    int t0 = (blockIdx.x & 3) * 64;
    int ic = (threadIdx.x & 31) * 8;
    int tq = threadIdx.x >> 5;          // 0..7
#pragma unroll
    for (int p = 0; p < 8; ++p) {
        int t = t0 + tq * 8 + p;
        const float* src = x + ((long)b * TT + t) * II + ic;
        float4 a = *(const float4*)src;
        float4 bb = *(const float4*)(src + 4);
        u16x8 u;
        u[0]=f2bf(a.x); u[1]=f2bf(a.y); u[2]=f2bf(a.z); u[3]=f2bf(a.w);
        u[4]=f2bf(bb.x); u[5]=f2bf(bb.y); u[6]=f2bf(bb.z); u[7]=f2bf(bb.w);
        *(u16x8*)(xt + ((long)t * BATCH + b) * II + ic) = u;
    }
}

// ---------------- persistent LSTM recurrence ----------------
// 16 groups (32 batch rows) x 16 WGs (32 h-cols x 4 gates each).
// h exchange: coalesced 16B sc0/sc1 stores to a 2MB MALL-hot ring (grp, t&3);
// separate plain cached stores to hs for the attn kernel (next dispatch).
// Flags: 16 bytes per (grp,t); producers store 1 byte, consumer polls one dwordx4.
__global__ __launch_bounds__(256, 1) void lstm_persist(
    const float* __restrict__ Wih, const float* __restrict__ Whh,
    const float* __restrict__ bih, const float* __restrict__ bhh,
    const unsigned short* __restrict__ xb,   // (T,B,I) bf16
    unsigned short* __restrict__ hs,         // (B,T,H) bf16  (ws, cached)
    unsigned short* __restrict__ ring,       // [16 grp][4][32][512] bf16 (ws, uncached)
    unsigned char* __restrict__ flags)       // [16 grp][256 t][16 B], zeroed per launch
{
    const int tid  = threadIdx.x;
    const int bx   = blockIdx.x;
    const int grp  = bx >> 4;                            // batch slice
    const int wg   = bx & 15;                            // gate-col slice
    const int w    = tid >> 6;                           // wave 0..3
    const int lane = tid & 63;
    const int quad = lane >> 4;
    const int ct   = lane & 15;
    const bool lo  = (ct < 8);
    const int rb0  = grp * 32;                           // batch rows [rb0, rb0+32)
    const int hcol = wg * 32 + w * 8 + (ct & 7);

    __shared__ unsigned short sh[32 * 528];              // h(t-1) tile; 528=264 dw, 264%32=8 -> 2-way only
    __shared__ unsigned short wlds[128 * 272];           // Whh[:,256:512]; 272=136 dw, 136%32=8 -> 2-way only
    __shared__ unsigned short sh2[32 * 32];              // h(t) transpose-out tile (this WG's 32 cols)

    // W rows for this lane's two n-tiles: nt0 -> gates {i,f}, nt1 -> gates {g,o}
    int wrow[2];
    wrow[0] = ((ct >> 3) + 0) * HH + hcol;
    wrow[1] = ((ct >> 3) + 2) * HH + hcol;

    // ---- register weights: Wih (K=256) + Whh low half (K=0..255) ----
    bfrag wih_f[8][2], whh_r[8][2];
#pragma unroll
    for (int kk = 0; kk < 8; ++kk)
#pragma unroll
        for (int nt = 0; nt < 2; ++nt) {
            wih_f[kk][nt] = cvt8(Wih + (long)wrow[nt] * II + kk * 32 + quad * 8);
            whh_r[kk][nt] = cvt8(Whh + (long)wrow[nt] * HH + kk * 32 + quad * 8);
        }

    // ---- LDS weights: Whh high half (K=256..511), 128 local gate-cols x 256 ----
    for (int e = tid * 8; e < 128 * 256; e += 256 * 8) {
        int lc = e >> 8;                  // local gate-col 0..127 (= gate*32 + col-in-wg)
        int k  = e & 255;
        int row = (lc >> 5) * HH + wg * 32 + (lc & 31);
        bfrag f = cvt8(Whh + (long)row * HH + 256 + k);
        *(u16x8*)(wlds + lc * 272 + k) = __builtin_bit_cast(u16x8, f);
    }
    __syncthreads();

    const int wl0 = ((((ct >> 3) + 0) * 32 + w * 8 + (ct & 7)) * 272) + quad * 8;
    const int wl1 = ((((ct >> 3) + 2) * 32 + w * 8 + (ct & 7)) * 272) + quad * 8;

    float bb[2];
    bb[0] = bih[wrow[0]] + bhh[wrow[0]];
    bb[1] = bih[wrow[1]] + bhh[wrow[1]];

    float cst[2][4];                                    // fp32 cell state, never rounded
#pragma unroll
    for (int mt = 0; mt < 2; ++mt)
#pragma unroll
        for (int r = 0; r < 4; ++r) cst[mt][r] = 0.f;

    f32x4 acc[2][2];
    // ---- x part for t=0 (pre-loop) ----
#pragma unroll
    for (int mt = 0; mt < 2; ++mt)
#pragma unroll
        for (int nt = 0; nt < 2; ++nt)
            acc[mt][nt] = (f32x4){bb[nt], bb[nt], bb[nt], bb[nt]};
#pragma unroll
    for (int kk = 0; kk < 8; ++kk)
#pragma unroll
        for (int mt = 0; mt < 2; ++mt) {
            bfrag a = ld8(xb + ((long)0 * BATCH + rb0 + mt * 16 + ct) * II + kk * 32 + quad * 8);
#pragma unroll
            for (int nt = 0; nt < 2; ++nt)
                acc[mt][nt] = __builtin_amdgcn_mfma_f32_16x16x32_bf16(a, wih_f[kk][nt], acc[mt][nt], 0, 0, 0);
        }

    for (int t = 0; t < TT; ++t) {
        if (t > 0) {
            // ---- wait: one lane polls one 16B flag word for all 16 producers ----
            if (tid == 0) {
                const unsigned char* fp = flags + (((long)grp * TT + (t - 1)) << 4);
                u32x4 fv;
                do {
                    asm volatile("global_load_dwordx4 %0, %1, off sc0 sc1\n\ts_waitcnt vmcnt(0)"
                                 : "=v"(fv) : "v"(fp) : "memory");
                } while (fv.x != 0x01010101u || fv.y != 0x01010101u ||
                         fv.z != 0x01010101u || fv.w != 0x01010101u);
            }
            __syncthreads();

            // ---- stage h(t-1) 32x512 bf16 from MALL-hot ring -> LDS ----
            const unsigned short* rbase = ring + (((long)grp * 4 + ((t - 1) & 3)) * 32) * HH;
            u32x4 vv[8];
#pragma unroll
            for (int j = 0; j < 8; ++j) {
                int cid = j * 256 + tid;               // 2048 x 16B chunks
                int row = cid >> 6, c16 = cid & 63;
                const unsigned short* p = rbase + row * HH + c16 * 8;
                asm volatile("global_load_dwordx4 %0, %1, off sc0 sc1"
                             : "=v"(vv[j]) : "v"(p));
            }
            asm volatile("s_waitcnt vmcnt(0)" ::: "memory");
#pragma unroll
            for (int j = 0; j < 8; ++j) {
                int cid = j * 256 + tid;
                int row = cid >> 6, c16 = cid & 63;
                *(u32x4*)(sh + row * 528 + c16 * 8) = vv[j];
            }
            __syncthreads();

            // ---- h part, K=0..255: B from registers ----
#pragma unroll
            for (int kk = 0; kk < 8; ++kk) {
                bfrag a[2];
#pragma unroll
                for (int mt = 0; mt < 2; ++mt)
                    a[mt] = ld8(sh + (mt * 16 + ct) * 528 + kk * 32 + quad * 8);
#pragma unroll
                for (int mt = 0; mt < 2; ++mt)
#pragma unroll
                    for (int nt = 0; nt < 2; ++nt)
                        acc[mt][nt] = __builtin_amdgcn_mfma_f32_16x16x32_bf16(a[mt], whh_r[kk][nt], acc[mt][nt], 0, 0, 0);
            }
            // ---- h part, K=256..511: B from LDS ----
#pragma unroll
            for (int kk = 0; kk < 8; ++kk) {
                bfrag a[2], b[2];
#pragma unroll
                for (int mt = 0; mt < 2; ++mt)
                    a[mt] = ld8(sh + (mt * 16 + ct) * 528 + (8 + kk) * 32 + quad * 8);
                b[0] = ld8(wlds + wl0 + kk * 32);
                b[1] = ld8(wlds + wl1 + kk * 32);
#pragma unroll
                for (int mt = 0; mt < 2; ++mt)
#pragma unroll
                    for (int nt = 0; nt < 2; ++nt)
                        acc[mt][nt] = __builtin_amdgcn_mfma_f32_16x16x32_bf16(a[mt], b[nt], acc[mt][nt], 0, 0, 0);
            }
        }

        // ---- elementwise epilogue; lanes l and l^8 hold complementary gate pairs ----
#pragma unroll
        for (int mt = 0; mt < 2; ++mt) {
#pragma unroll
            for (int r = 0; r < 4; ++r) {
                float a0 = acc[mt][0][r], a1 = acc[mt][1][r];
                float b0 = __shfl_xor(a0, 8, 64);
                float b1 = __shfl_xor(a1, 8, 64);
                float iv = lo ? a0 : b0;
                float fv = lo ? b0 : a0;
                float gv = lo ? a1 : b1;
                float ov = lo ? b1 : a1;
                iv = sigm(iv); fv = sigm(fv); gv = tanh_(gv); ov = sigm(ov);
                float c = fv * cst[mt][r] + iv * gv;
                cst[mt][r] = c;
                float h = ov * tanh_(c);
                if (lo)
                    sh2[(mt * 16 + quad * 4 + r) * 32 + w * 8 + (ct & 7)] = f2bf(h);
            }
        }
        __syncthreads();

        // ---- coalesced dual store: 32 rows x 64B. tid<128: one 16B chunk each ----
        if (tid < 128) {
            int row = tid >> 2, c = tid & 3;
            u32x4 v = *(const u32x4*)(sh2 + row * 32 + c * 8);
            // cached store for attn
            *(u32x4*)(hs + ((long)(rb0 + row) * TT + t) * HH + wg * 32 + c * 8) = v;
            // uncached store to exchange ring
            unsigned short* rp = ring + (((long)grp * 4 + (t & 3)) * 32 + row) * HH + wg * 32 + c * 8;
            asm volatile("global_store_dwordx4 %0, %1, off sc0 sc1"
                         :: "v"(rp), "v"(v) : "memory");
        }

        // ---- x part for t+1: overlaps with ring-store drain ----
        if (t < TT - 1) {
#pragma unroll
            for (int mt = 0; mt < 2; ++mt)
#pragma unroll
                for (int nt = 0; nt < 2; ++nt)
                    acc[mt][nt] = (f32x4){bb[nt], bb[nt], bb[nt], bb[nt]};
#pragma unroll
            for (int kk = 0; kk < 8; ++kk)
#pragma unroll
                for (int mt = 0; mt < 2; ++mt) {
                    bfrag a = ld8(xb + ((long)(t + 1) * BATCH + rb0 + mt * 16 + ct) * II + kk * 32 + quad * 8);
#pragma unroll
                    for (int nt = 0; nt < 2; ++nt)
                        acc[mt][nt] = __builtin_amdgcn_mfma_f32_16x16x32_bf16(a, wih_f[kk][nt], acc[mt][nt], 0, 0, 0);
                }

            // ---- publish: drain own stores, barrier, then one flag byte ----
            asm volatile("s_waitcnt vmcnt(0)" ::: "memory");
            __syncthreads();
            if (tid == 0) {
                unsigned one = 1u;
                unsigned char* p = flags + ((((long)grp * TT + t) << 4) | wg);
                asm volatile("global_store_byte %0, %1, off sc0 sc1"
                             :: "v"(p), "v"(one) : "memory");
            }
        }
    }
}

// ---------------- attention pooling ----------------
__global__ __launch_bounds__(256) void attn_kernel(const unsigned short* __restrict__ hs,
                                                   float* __restrict__ out) {
    int b = blockIdx.x, tid = threadIdx.x;
    int w = tid >> 6, lane = tid & 63;
    __shared__ float sc[TT];
    __shared__ float hl[HH];
    for (int c = tid; c < HH; c += 256)
        hl[c] = bf2f(hs[((long)b * TT + (TT - 1)) * HH + c]);
    __syncthreads();
    float hr[8];
#pragma unroll
    for (int j = 0; j < 8; ++j) hr[j] = hl[lane * 8 + j];
    for (int t = w; t < TT; t += 4) {                 // scores, wave-parallel over t
        u16x8 hv = *(const u16x8*)(hs + ((long)b * TT + t) * HH + lane * 8);
        float p = 0.f;
#pragma unroll
        for (int j = 0; j < 8; ++j) p += bf2f(hv[j]) * hr[j];
#pragma unroll
        for (int off = 32; off; off >>= 1) p += __shfl_xor(p, off, 64);
        if (lane == 0) sc[t] = p;
    }
    __syncthreads();
    float denom = 0.f;
    for (int t = 0; t < TT; ++t) denom += sc[t];
    float c0 = 0.f, c1 = 0.f;
    int col = tid * 2;
    for (int t = 0; t < TT; ++t) {
        float s = sc[t];
        unsigned v = *(const unsigned*)(hs + ((long)b * TT + t) * HH + col);
        c0 += s * __uint_as_float((v & 0xffffu) << 16);
        c1 += s * __uint_as_float(v & 0xffff0000u);
    }
    out[(long)b * HH + col]     = c0 / denom;
    out[(long)b * HH + col + 1] = c1 / denom;
}

extern "C" void kernel_launch(void* const* d_in, const int* in_sizes, int n_in,
                              void* d_out, int out_size, void* d_ws, size_t ws_size,
                              hipStream_t stream) {
    const float* x   = (const float*)d_in[0];
    const float* Wih = (const float*)d_in[1];
    const float* Whh = (const float*)d_in[2];
    const float* bih = (const float*)d_in[3];
    const float* bhh = (const float*)d_in[4];
    float* out = (float*)d_out;

    char* ws = (char*)d_ws;
    unsigned char*  flags = (unsigned char*)ws;                              // 64 KB
    unsigned short* ring  = (unsigned short*)(ws + 65536);                   // 2 MB
    unsigned short* hs    = (unsigned short*)(ws + 65536 + 2097152);         // 134.2 MB
    unsigned short* xb    = (unsigned short*)(ws + 65536 + 2097152 + (size_t)BATCH * TT * HH * 2);

    (void)hipMemsetAsync(flags, 0, 65536, stream);   // flags move 0->1 only
    cast_x_kernel<<<BATCH * (TT / 64), 256, 0, stream>>>(x, xb);
    lstm_persist<<<256, 256, 0, stream>>>(Wih, Whh, bih, bhh, xb, hs, ring, flags);
    attn_kernel<<<BATCH, 256, 0, stream>>>(hs, out);
}

// Round 7
// 1825.347 us; speedup vs baseline: 1.1010x; 1.1010x over previous
//
#include <hip/hip_runtime.h>

#define BATCH 512
#define TT    256
#define II    256
#define HH    512

typedef float f32x4  __attribute__((ext_vector_type(4)));
typedef unsigned u32x4 __attribute__((ext_vector_type(4)));
typedef unsigned short u16x8 __attribute__((ext_vector_type(8)));
typedef short bfrag  __attribute__((ext_vector_type(8)));   // 8 bf16 = 4 VGPRs (MFMA A/B operand)

__device__ inline unsigned short f2bf(float f) {
    unsigned u = __float_as_uint(f);
    return (unsigned short)((u + 0x7fffu + ((u >> 16) & 1u)) >> 16);   // RNE
}
__device__ inline float bf2f(unsigned short h) { return __uint_as_float(((unsigned)h) << 16); }

__device__ inline bfrag cvt8(const float* p) {   // 8 fp32 -> bf16 frag
    float4 a = *(const float4*)p;
    float4 b = *(const float4*)(p + 4);
    u16x8 u;
    u[0]=f2bf(a.x); u[1]=f2bf(a.y); u[2]=f2bf(a.z); u[3]=f2bf(a.w);
    u[4]=f2bf(b.x); u[5]=f2bf(b.y); u[6]=f2bf(b.z); u[7]=f2bf(b.w);
    return __builtin_bit_cast(bfrag, u);
}
__device__ inline bfrag ld8(const unsigned short* p) {
    return __builtin_bit_cast(bfrag, *(const u16x8*)p);
}
__device__ inline float sigm(float x) { return 1.f / (1.f + __expf(-x)); }
__device__ inline float tanh_(float x) {       // overflow-safe tanh via exp
    float ax = fabsf(x);
    float e  = __expf(-2.f * ax);
    float t  = (1.f - e) / (1.f + e);
    return copysignf(t, x);
}

// ---------------- x -> bf16 cast + transpose (B,T,I) -> (T,B,I) ----------------
__global__ __launch_bounds__(256) void cast_x_kernel(const float* __restrict__ x,
                                                     unsigned short* __restrict__ xt) {
    int b  = blockIdx.x >> 2;
    int t0 = (blockIdx.x & 3) * 64;
    int ic = (threadIdx.x & 31) * 8;
    int tq = threadIdx.x >> 5;          // 0..7
#pragma unroll
    for (int p = 0; p < 8; ++p) {
        int t = t0 + tq * 8 + p;
        const float* src = x + ((long)b * TT + t) * II + ic;
        float4 a = *(const float4*)src;
        float4 bb = *(const float4*)(src + 4);
        u16x8 u;
        u[0]=f2bf(a.x); u[1]=f2bf(a.y); u[2]=f2bf(a.z); u[3]=f2bf(a.w);
        u[4]=f2bf(bb.x); u[5]=f2bf(bb.y); u[6]=f2bf(bb.z); u[7]=f2bf(bb.w);
        *(u16x8*)(xt + ((long)t * BATCH + b) * II + ic) = u;
    }
}

// ---------------- persistent LSTM recurrence ----------------
// 16 groups (32 batch rows) x 16 WGs (32 h-cols x 4 gates each).
// grp = bx&15: under the %8 XCD round-robin heuristic all 16 WGs of a group
// share one XCD (2 groups/XCD). h exchange = hs itself (write-once slots):
//   producer: sc0 sc1 stores (MALL, L2 never dirty -> no stale-line hazard)
//   consumer: sc0-only loads (miss->MALL = always correct; same-XCD siblings
//             then hit L2 at ~250cyc -> perf only, no correctness dependence)
// Flags stay sc0 sc1 (an L2-cached not-ready flag would deadlock).
// Publish is barrier-free: waves 0/1 drain own stores, store own flag byte.
__global__ __launch_bounds__(256, 1) void lstm_persist(
    const float* __restrict__ Wih, const float* __restrict__ Whh,
    const float* __restrict__ bih, const float* __restrict__ bhh,
    const unsigned short* __restrict__ xb,   // (T,B,I) bf16
    unsigned short* __restrict__ hs,         // (B,T,H) bf16  (ws; sc0sc1-written)
    unsigned char* __restrict__ flags)       // [16 grp][256 t][32 B], zeroed per launch
{
    const int tid  = threadIdx.x;
    const int bx   = blockIdx.x;
    const int grp  = bx & 15;                            // batch slice (XCD-local set)
    const int wg   = bx >> 4;                            // gate-col slice
    const int w    = tid >> 6;                           // wave 0..3
    const int lane = tid & 63;
    const int quad = lane >> 4;
    const int ct   = lane & 15;
    const bool lo  = (ct < 8);
    const int rb0  = grp * 32;                           // batch rows [rb0, rb0+32)
    const int hcol = wg * 32 + w * 8 + (ct & 7);

    __shared__ unsigned short sh[32 * 528];              // h(t-1) tile; 264 dw % 32 = 8 -> free 2-way
    __shared__ unsigned short wlds[128 * 272];           // Whh[:,256:512]; 136 dw % 32 = 8 -> free 2-way
    __shared__ unsigned short sh2[32 * 32];              // h(t) transpose-out tile

    int wrow[2];
    wrow[0] = ((ct >> 3) + 0) * HH + hcol;
    wrow[1] = ((ct >> 3) + 2) * HH + hcol;

    // ---- register weights: Wih (K=256) + Whh low half (K=0..255) ----
    bfrag wih_f[8][2], whh_r[8][2];
#pragma unroll
    for (int kk = 0; kk < 8; ++kk)
#pragma unroll
        for (int nt = 0; nt < 2; ++nt) {
            wih_f[kk][nt] = cvt8(Wih + (long)wrow[nt] * II + kk * 32 + quad * 8);
            whh_r[kk][nt] = cvt8(Whh + (long)wrow[nt] * HH + kk * 32 + quad * 8);
        }

    // ---- LDS weights: Whh high half (K=256..511) ----
    for (int e = tid * 8; e < 128 * 256; e += 256 * 8) {
        int lc = e >> 8;
        int k  = e & 255;
        int row = (lc >> 5) * HH + wg * 32 + (lc & 31);
        bfrag f = cvt8(Whh + (long)row * HH + 256 + k);
        *(u16x8*)(wlds + lc * 272 + k) = __builtin_bit_cast(u16x8, f);
    }
    __syncthreads();

    const int wl0 = ((((ct >> 3) + 0) * 32 + w * 8 + (ct & 7)) * 272) + quad * 8;
    const int wl1 = ((((ct >> 3) + 2) * 32 + w * 8 + (ct & 7)) * 272) + quad * 8;

    float bb[2];
    bb[0] = bih[wrow[0]] + bhh[wrow[0]];
    bb[1] = bih[wrow[1]] + bhh[wrow[1]];

    float cst[2][4];
#pragma unroll
    for (int mt = 0; mt < 2; ++mt)
#pragma unroll
        for (int r = 0; r < 4; ++r) cst[mt][r] = 0.f;

    f32x4 acc[2][2];
    // ---- x part for t=0 (pre-loop) ----
#pragma unroll
    for (int mt = 0; mt < 2; ++mt)
#pragma unroll
        for (int nt = 0; nt < 2; ++nt)
            acc[mt][nt] = (f32x4){bb[nt], bb[nt], bb[nt], bb[nt]};
#pragma unroll
    for (int kk = 0; kk < 8; ++kk)
#pragma unroll
        for (int mt = 0; mt < 2; ++mt) {
            bfrag a = ld8(xb + ((long)(rb0 + mt * 16 + ct)) * II + kk * 32 + quad * 8);
#pragma unroll
            for (int nt = 0; nt < 2; ++nt)
                acc[mt][nt] = __builtin_amdgcn_mfma_f32_16x16x32_bf16(a, wih_f[kk][nt], acc[mt][nt], 0, 0, 0);
        }

    for (int t = 0; t < TT; ++t) {
        if (t > 0) {
            // ---- wait: one lane polls 32 flag bytes (2 x dwordx4) ----
            if (tid == 0) {
                const unsigned char* fp = flags + (((long)grp * TT + (t - 1)) << 5);
                u32x4 f0, f1;
                do {
                    asm volatile("global_load_dwordx4 %0, %2, off sc0 sc1\n\t"
                                 "global_load_dwordx4 %1, %2, off offset:16 sc0 sc1\n\t"
                                 "s_waitcnt vmcnt(0)"
                                 : "=v"(f0), "=v"(f1) : "v"(fp) : "memory");
                } while (f0.x != 0x01010101u || f0.y != 0x01010101u ||
                         f0.z != 0x01010101u || f0.w != 0x01010101u ||
                         f1.x != 0x01010101u || f1.y != 0x01010101u ||
                         f1.z != 0x01010101u || f1.w != 0x01010101u);
            }
            __syncthreads();

            // ---- stage h(t-1) 32x512 bf16 -> LDS; sc0-only (L2-fill) loads,
            //      chunk order rotated by wg so first-touch MALL misses spread ----
            u32x4 vv[8];
#pragma unroll
            for (int j = 0; j < 8; ++j) {
                int cid = (j * 256 + tid + (wg << 7)) & 2047;
                int row = cid >> 6, c16 = cid & 63;
                const unsigned short* p = hs + ((long)(rb0 + row) * TT + (t - 1)) * HH + c16 * 8;
                asm volatile("global_load_dwordx4 %0, %1, off sc0"
                             : "=v"(vv[j]) : "v"(p));
            }
            asm volatile("s_waitcnt vmcnt(0)" ::: "memory");
#pragma unroll
            for (int j = 0; j < 8; ++j) {
                int cid = (j * 256 + tid + (wg << 7)) & 2047;
                int row = cid >> 6, c16 = cid & 63;
                *(u32x4*)(sh + row * 528 + c16 * 8) = vv[j];
            }
            __syncthreads();

            // ---- h part, K=0..255: B from registers ----
#pragma unroll
            for (int kk = 0; kk < 8; ++kk) {
                bfrag a[2];
#pragma unroll
                for (int mt = 0; mt < 2; ++mt)
                    a[mt] = ld8(sh + (mt * 16 + ct) * 528 + kk * 32 + quad * 8);
#pragma unroll
                for (int mt = 0; mt < 2; ++mt)
#pragma unroll
                    for (int nt = 0; nt < 2; ++nt)
                        acc[mt][nt] = __builtin_amdgcn_mfma_f32_16x16x32_bf16(a[mt], whh_r[kk][nt], acc[mt][nt], 0, 0, 0);
            }
            // ---- h part, K=256..511: B from LDS ----
#pragma unroll
            for (int kk = 0; kk < 8; ++kk) {
                bfrag a[2], b[2];
#pragma unroll
                for (int mt = 0; mt < 2; ++mt)
                    a[mt] = ld8(sh + (mt * 16 + ct) * 528 + (8 + kk) * 32 + quad * 8);
                b[0] = ld8(wlds + wl0 + kk * 32);
                b[1] = ld8(wlds + wl1 + kk * 32);
#pragma unroll
                for (int mt = 0; mt < 2; ++mt)
#pragma unroll
                    for (int nt = 0; nt < 2; ++nt)
                        acc[mt][nt] = __builtin_amdgcn_mfma_f32_16x16x32_bf16(a[mt], b[nt], acc[mt][nt], 0, 0, 0);
            }
        }

        // ---- elementwise epilogue -> sh2 transpose tile ----
#pragma unroll
        for (int mt = 0; mt < 2; ++mt) {
#pragma unroll
            for (int r = 0; r < 4; ++r) {
                float a0 = acc[mt][0][r], a1 = acc[mt][1][r];
                float b0 = __shfl_xor(a0, 8, 64);
                float b1 = __shfl_xor(a1, 8, 64);
                float iv = lo ? a0 : b0;
                float fv = lo ? b0 : a0;
                float gv = lo ? a1 : b1;
                float ov = lo ? b1 : a1;
                iv = sigm(iv); fv = sigm(fv); gv = tanh_(gv); ov = sigm(ov);
                float c = fv * cst[mt][r] + iv * gv;
                cst[mt][r] = c;
                float h = ov * tanh_(c);
                if (lo)
                    sh2[(mt * 16 + quad * 4 + r) * 32 + w * 8 + (ct & 7)] = f2bf(h);
            }
        }
        __syncthreads();

        // ---- barrier-free publish: waves 0/1 store 16B chunks, drain own, flag own ----
        if (tid < 128) {
            int row = tid >> 2, c = tid & 3;
            u32x4 v = *(const u32x4*)(sh2 + row * 32 + c * 8);
            unsigned short* p = hs + ((long)(rb0 + row) * TT + t) * HH + wg * 32 + c * 8;
            asm volatile("global_store_dwordx4 %0, %1, off sc0 sc1"
                         :: "v"(p), "v"(v) : "memory");
            if (t < TT - 1) {
                asm volatile("s_waitcnt vmcnt(0)" ::: "memory");
                if ((tid & 63) == 0) {
                    unsigned one = 1u;
                    unsigned char* fp2 = flags + ((((long)grp * TT + t) << 5) | (wg * 2 + w));
                    asm volatile("global_store_byte %0, %1, off sc0 sc1"
                                 :: "v"(fp2), "v"(one) : "memory");
                }
            }
        }

        // ---- x part for t+1 (after publish: overlaps other WGs' polls) ----
        if (t < TT - 1) {
#pragma unroll
            for (int mt = 0; mt < 2; ++mt)
#pragma unroll
                for (int nt = 0; nt < 2; ++nt)
                    acc[mt][nt] = (f32x4){bb[nt], bb[nt], bb[nt], bb[nt]};
#pragma unroll
            for (int kk = 0; kk < 8; ++kk)
#pragma unroll
                for (int mt = 0; mt < 2; ++mt) {
                    bfrag a = ld8(xb + ((long)(t + 1) * BATCH + rb0 + mt * 16 + ct) * II + kk * 32 + quad * 8);
#pragma unroll
                    for (int nt = 0; nt < 2; ++nt)
                        acc[mt][nt] = __builtin_amdgcn_mfma_f32_16x16x32_bf16(a, wih_f[kk][nt], acc[mt][nt], 0, 0, 0);
                }
        }
    }
}

// ---------------- attention pooling ----------------
__global__ __launch_bounds__(256) void attn_kernel(const unsigned short* __restrict__ hs,
                                                   float* __restrict__ out) {
    int b = blockIdx.x, tid = threadIdx.x;
    int w = tid >> 6, lane = tid & 63;
    __shared__ float sc[TT];
    __shared__ float hl[HH];
    for (int c = tid; c < HH; c += 256)
        hl[c] = bf2f(hs[((long)b * TT + (TT - 1)) * HH + c]);
    __syncthreads();
    float hr[8];
#pragma unroll
    for (int j = 0; j < 8; ++j) hr[j] = hl[lane * 8 + j];
    for (int t = w; t < TT; t += 4) {
        u16x8 hv = *(const u16x8*)(hs + ((long)b * TT + t) * HH + lane * 8);
        float p = 0.f;
#pragma unroll
        for (int j = 0; j < 8; ++j) p += bf2f(hv[j]) * hr[j];
#pragma unroll
        for (int off = 32; off; off >>= 1) p += __shfl_xor(p, off, 64);
        if (lane == 0) sc[t] = p;
    }
    __syncthreads();
    float denom = 0.f;
    for (int t = 0; t < TT; ++t) denom += sc[t];
    float c0 = 0.f, c1 = 0.f;
    int col = tid * 2;
    for (int t = 0; t < TT; ++t) {
        float s = sc[t];
        unsigned v = *(const unsigned*)(hs + ((long)b * TT + t) * HH + col);
        c0 += s * __uint_as_float((v & 0xffffu) << 16);
        c1 += s * __uint_as_float(v & 0xffff0000u);
    }
    out[(long)b * HH + col]     = c0 / denom;
    out[(long)b * HH + col + 1] = c1 / denom;
}

extern "C" void kernel_launch(void* const* d_in, const int* in_sizes, int n_in,
                              void* d_out, int out_size, void* d_ws, size_t ws_size,
                              hipStream_t stream) {
    const float* x   = (const float*)d_in[0];
    const float* Wih = (const float*)d_in[1];
    const float* Whh = (const float*)d_in[2];
    const float* bih = (const float*)d_in[3];
    const float* bhh = (const float*)d_in[4];
    float* out = (float*)d_out;

    char* ws = (char*)d_ws;
    unsigned char*  flags = (unsigned char*)ws;                              // 128 KB
    unsigned short* hs    = (unsigned short*)(ws + 131072);                  // 134.2 MB
    unsigned short* xb    = (unsigned short*)(ws + 131072 + (size_t)BATCH * TT * HH * 2);

    (void)hipMemsetAsync(flags, 0, 131072, stream);   // flags move 0->1 only
    cast_x_kernel<<<BATCH * (TT / 64), 256, 0, stream>>>(x, xb);
    lstm_persist<<<256, 256, 0, stream>>>(Wih, Whh, bih, bhh, xb, hs, flags);
    attn_kernel<<<BATCH, 256, 0, stream>>>(hs, out);
}